// Round 2
// baseline (1339.823 us; speedup 1.0000x reference)
//
#include <hip/hip_runtime.h>

constexpr int kN  = 50000;
constexpr int kE  = 400000;
constexpr int kH  = 4;
constexpr int kHC = 128;
constexpr int kED = 32;
constexpr int kL  = 2;
#define EPS_LN 1e-5f
#define NEG_SLOPE 0.01f
#define RSQRT_C 0.17677669529663687f  // 1/sqrt(32)

// ---------------- Projections: q,k,v,xr = h @ {Wq,Wk,Wv,Wskip} + b ----------
__global__ __launch_bounds__(256) void proj_kernel(
    const float* __restrict__ hin,
    const float* __restrict__ Wq, const float* __restrict__ bq,
    const float* __restrict__ Wk, const float* __restrict__ bk,
    const float* __restrict__ Wv, const float* __restrict__ bv,
    const float* __restrict__ Ws, const float* __restrict__ bs,
    float* __restrict__ q, float* __restrict__ k,
    float* __restrict__ v, float* __restrict__ xr)
{
    __shared__ float xs[16 * kHC];
    const int t = threadIdx.x;
    const int row0 = blockIdx.x * 16;
    // cooperative load of 16x128 fp32 tile (8 KB) via float4
    const float4* s4 = (const float4*)(hin + (size_t)row0 * kHC);
    float4* d4 = (float4*)xs;
    d4[t] = s4[t];
    d4[t + 256] = s4[t + 256];
    __syncthreads();

    const int c = t & 127;       // output column
    const int half = t >> 7;     // 0/1 -> rows 0-7 / 8-15
    float acc0[8], acc1[8], acc2[8], acc3[8];
#pragma unroll
    for (int r = 0; r < 8; r++) { acc0[r] = 0.f; acc1[r] = 0.f; acc2[r] = 0.f; acc3[r] = 0.f; }
    const float* xbase = xs + (half * 8) * kHC;

    for (int k4 = 0; k4 < kHC; k4 += 4) {
        float4 xv[8];
#pragma unroll
        for (int r = 0; r < 8; r++) xv[r] = *(const float4*)(xbase + r * kHC + k4);
#pragma unroll
        for (int i = 0; i < 4; i++) {
            const int ki = k4 + i;
            const float wq = Wq[ki * kHC + c];
            const float wk = Wk[ki * kHC + c];
            const float wv = Wv[ki * kHC + c];
            const float wsv = Ws[ki * kHC + c];
#pragma unroll
            for (int r = 0; r < 8; r++) {
                const float xvi = ((const float*)&xv[r])[i];
                acc0[r] = fmaf(xvi, wq, acc0[r]);
                acc1[r] = fmaf(xvi, wk, acc1[r]);
                acc2[r] = fmaf(xvi, wv, acc2[r]);
                acc3[r] = fmaf(xvi, wsv, acc3[r]);
            }
        }
    }
    const float bqv = bq[c], bkv = bk[c], bvv = bv[c], bsv = bs[c];
#pragma unroll
    for (int r = 0; r < 8; r++) {
        const size_t o = (size_t)(row0 + half * 8 + r) * kHC + c;
        q[o]  = acc0[r] + bqv;
        k[o]  = acc1[r] + bkv;
        v[o]  = acc2[r] + bvv;
        xr[o] = acc3[r] + bsv;
    }
}

// ---------------- Edge pass: alpha, exp, scatter unnormalized messages ------
// 1 wave = 1 edge; lane handles channels (2*lane, 2*lane+1); 16-lane group = head.
__global__ __launch_bounds__(256) void edge_kernel(
    const float* __restrict__ q, const float* __restrict__ kk,
    const float* __restrict__ vv, const float* __restrict__ ea,
    const float* __restrict__ We, const float* __restrict__ be,
    const int* __restrict__ srcI, const int* __restrict__ dstI,
    float* __restrict__ asum, float* __restrict__ agg)
{
    const int t = threadIdx.x;
    const int eid = blockIdx.x * 4 + (t >> 6);
    if (eid >= kE) return;
    const int lane = t & 63;
    const int c = lane << 1;

    const int s = srcI[eid];
    const int d = dstI[eid];

    // e = edge_attr @ We + be  (2 channels per lane)
    float e0 = be[c], e1 = be[c + 1];
    const float* ar = ea + (size_t)eid * kED;
#pragma unroll
    for (int j = 0; j < kED; j++) {
        const float a = ar[j];
        const float2 w = *(const float2*)&We[j * kHC + c];
        e0 = fmaf(a, w.x, e0);
        e1 = fmaf(a, w.y, e1);
    }

    const float2 qv = *(const float2*)&q[(size_t)d * kHC + c];
    const float2 kv = *(const float2*)&kk[(size_t)s * kHC + c];
    float p = qv.x * (kv.x + e0) + qv.y * (kv.y + e1);
    // reduce over the 16-lane head group (butterfly -> all lanes have sum)
    p += __shfl_xor(p, 1);
    p += __shfl_xor(p, 2);
    p += __shfl_xor(p, 4);
    p += __shfl_xor(p, 8);

    const float aex = __expf(p * RSQRT_C);
    if ((lane & 15) == 0) {
        atomicAdd(&asum[d * kH + (lane >> 4)], aex);
    }
    const float2 vl = *(const float2*)&vv[(size_t)s * kHC + c];
    atomicAdd(&agg[(size_t)d * kHC + c],     (vl.x + e0) * aex);
    atomicAdd(&agg[(size_t)d * kHC + c + 1], (vl.y + e1) * aex);
}

// ---------------- Node epilogue: normalize, beta-gate, LayerNorm, LeakyReLU -
__global__ __launch_bounds__(256) void node_kernel(
    const float* __restrict__ agg, const float* __restrict__ asum,
    const float* __restrict__ xr, const float* __restrict__ Wb,
    const float* __restrict__ lnw, const float* __restrict__ lnb,
    float* __restrict__ hout)
{
    const int t = threadIdx.x;
    const int n = blockIdx.x * 4 + (t >> 6);
    const int lane = t & 63;
    const int c = lane << 1;
    const int h = c >> 5;

    float2 o = *(const float2*)&agg[(size_t)n * kHC + c];
    const float denom = asum[n * kH + h] + 1e-16f;
    o.x /= denom;
    o.y /= denom;
    const float2 r = *(const float2*)&xr[(size_t)n * kHC + c];

    float z = o.x * Wb[c] + o.y * Wb[c + 1]
            + r.x * Wb[kHC + c] + r.y * Wb[kHC + c + 1]
            + (o.x - r.x) * Wb[2 * kHC + c] + (o.y - r.y) * Wb[2 * kHC + c + 1];
#pragma unroll
    for (int m = 1; m < 64; m <<= 1) z += __shfl_xor(z, m);
    const float beta = 1.f / (1.f + __expf(-z));

    const float g0 = beta * r.x + (1.f - beta) * o.x;
    const float g1 = beta * r.y + (1.f - beta) * o.y;

    float sm = g0 + g1;
    float sq = g0 * g0 + g1 * g1;
#pragma unroll
    for (int m = 1; m < 64; m <<= 1) {
        sm += __shfl_xor(sm, m);
        sq += __shfl_xor(sq, m);
    }
    const float mu  = sm * (1.f / kHC);
    const float var = sq * (1.f / kHC) - mu * mu;
    const float inv = rsqrtf(var + EPS_LN);

    float y0 = (g0 - mu) * inv * lnw[c] + lnb[c];
    float y1 = (g1 - mu) * inv * lnw[c + 1] + lnb[c + 1];
    y0 = y0 > 0.f ? y0 : NEG_SLOPE * y0;
    y1 = y1 > 0.f ? y1 : NEG_SLOPE * y1;
    *(float2*)&hout[(size_t)n * kHC + c] = make_float2(y0, y1);
}

extern "C" void kernel_launch(void* const* d_in, const int* in_sizes, int n_in,
                              void* d_out, int out_size, void* d_ws, size_t ws_size,
                              hipStream_t stream)
{
    const float* x   = (const float*)d_in[0];
    const int*   ei  = (const int*)d_in[1];     // int64 in reference -> int32 here
    const float* ea  = (const float*)d_in[2];
    const float* Wq  = (const float*)d_in[3];
    const float* bq  = (const float*)d_in[4];
    const float* Wk  = (const float*)d_in[5];
    const float* bk  = (const float*)d_in[6];
    const float* Wv  = (const float*)d_in[7];
    const float* bv  = (const float*)d_in[8];
    const float* We  = (const float*)d_in[9];
    const float* be  = (const float*)d_in[10];
    const float* Wsk = (const float*)d_in[11];
    const float* bsk = (const float*)d_in[12];
    const float* Wb  = (const float*)d_in[13];
    const float* lnw = (const float*)d_in[14];
    const float* lnb = (const float*)d_in[15];
    float* out = (float*)d_out;

    float* ws   = (float*)d_ws;
    float* q    = ws;
    float* k    = q   + (size_t)kN * kHC;
    float* v    = k   + (size_t)kN * kHC;
    float* xr   = v   + (size_t)kN * kHC;
    float* agg  = xr  + (size_t)kN * kHC;
    float* asum = agg + (size_t)kN * kHC;

    const int* srcI = ei;
    const int* dstI = ei + kE;

    const float* hin = x;
    for (int l = 0; l < kL; l++) {
        hipMemsetAsync(asum, 0, (size_t)kN * kH * sizeof(float), stream);
        hipMemsetAsync(agg, 0, (size_t)kN * kHC * sizeof(float), stream);
        proj_kernel<<<kN / 16, 256, 0, stream>>>(
            hin,
            Wq + (size_t)l * kHC * kHC, bq + (size_t)l * kHC,
            Wk + (size_t)l * kHC * kHC, bk + (size_t)l * kHC,
            Wv + (size_t)l * kHC * kHC, bv + (size_t)l * kHC,
            Wsk + (size_t)l * kHC * kHC, bsk + (size_t)l * kHC,
            q, k, v, xr);
        edge_kernel<<<kE / 4, 256, 0, stream>>>(
            q, k, v, ea,
            We + (size_t)l * kED * kHC, be + (size_t)l * kHC,
            srcI, dstI, asum, agg);
        node_kernel<<<kN / 4, 256, 0, stream>>>(
            agg, asum, xr,
            Wb + (size_t)l * 3 * kHC, lnw + (size_t)l * kHC, lnb + (size_t)l * kHC,
            out);
        hin = out;
    }
}

// Round 4
// 856.246 us; speedup vs baseline: 1.5648x; 1.5648x over previous
//
#include <hip/hip_runtime.h>

constexpr int kN  = 50000;
constexpr int kE  = 400000;
constexpr int kH  = 4;
constexpr int kHC = 128;
constexpr int kED = 32;
constexpr int kL  = 2;
#define EPS_LN 1e-5f
#define NEG_SLOPE 0.01f
#define RSQRT_C 0.17677669529663687f  // 1/sqrt(32)

// ---------------- Projections: q,k,v,xr = h @ {Wq,Wk,Wv,Wskip} + b ----------
__global__ __launch_bounds__(256) void proj_kernel(
    const float* __restrict__ hin,
    const float* __restrict__ Wq, const float* __restrict__ bq,
    const float* __restrict__ Wk, const float* __restrict__ bk,
    const float* __restrict__ Wv, const float* __restrict__ bv,
    const float* __restrict__ Ws, const float* __restrict__ bs,
    float* __restrict__ q, float* __restrict__ k,
    float* __restrict__ v, float* __restrict__ xr)
{
    __shared__ float xs[16 * kHC];
    const int t = threadIdx.x;
    const int row0 = blockIdx.x * 16;
    const float4* s4 = (const float4*)(hin + (size_t)row0 * kHC);
    float4* d4 = (float4*)xs;
    d4[t] = s4[t];
    d4[t + 256] = s4[t + 256];
    __syncthreads();

    const int c = t & 127;       // output column
    const int half = t >> 7;     // rows 0-7 / 8-15
    float acc0[8], acc1[8], acc2[8], acc3[8];
#pragma unroll
    for (int r = 0; r < 8; r++) { acc0[r] = 0.f; acc1[r] = 0.f; acc2[r] = 0.f; acc3[r] = 0.f; }
    const float* xbase = xs + (half * 8) * kHC;

    for (int k4 = 0; k4 < kHC; k4 += 4) {
        float4 xv[8];
#pragma unroll
        for (int r = 0; r < 8; r++) xv[r] = *(const float4*)(xbase + r * kHC + k4);
#pragma unroll
        for (int i = 0; i < 4; i++) {
            const int ki = k4 + i;
            const float wq = Wq[ki * kHC + c];
            const float wk = Wk[ki * kHC + c];
            const float wv = Wv[ki * kHC + c];
            const float wsv = Ws[ki * kHC + c];
#pragma unroll
            for (int r = 0; r < 8; r++) {
                const float xvi = ((const float*)&xv[r])[i];
                acc0[r] = fmaf(xvi, wq, acc0[r]);
                acc1[r] = fmaf(xvi, wk, acc1[r]);
                acc2[r] = fmaf(xvi, wv, acc2[r]);
                acc3[r] = fmaf(xvi, wsv, acc3[r]);
            }
        }
    }
    const float bqv = bq[c], bkv = bk[c], bvv = bv[c], bsv = bs[c];
#pragma unroll
    for (int r = 0; r < 8; r++) {
        const size_t o = (size_t)(row0 + half * 8 + r) * kHC + c;
        q[o]  = acc0[r] + bqv;
        k[o]  = acc1[r] + bkv;
        v[o]  = acc2[r] + bvv;
        xr[o] = acc3[r] + bsv;
    }
}

// ---------------- CSR build (once per call; edge_index is call-constant) ----
__global__ __launch_bounds__(256) void hist_kernel(
    const int* __restrict__ dstI, int* __restrict__ deg)
{
    const int e = blockIdx.x * 256 + threadIdx.x;
    if (e < kE) atomicAdd(&deg[dstI[e]], 1);
}

__global__ __launch_bounds__(1024) void scan_kernel(
    const int* __restrict__ deg, int* __restrict__ rowptr, int* __restrict__ cursor)
{
    const int t = threadIdx.x;
    constexpr int CH = (kN + 1023) / 1024;  // 49
    const int base = t * CH;
    const int end = base + CH < kN ? base + CH : kN;
    int lsum = 0;
    for (int i = base; i < end; i++) lsum += deg[i];
    __shared__ int sm[1024];
    sm[t] = lsum;
    __syncthreads();
    for (int off = 1; off < 1024; off <<= 1) {
        const int x = (t >= off) ? sm[t - off] : 0;
        __syncthreads();
        sm[t] += x;
        __syncthreads();
    }
    int running = sm[t] - lsum;  // exclusive prefix
    for (int i = base; i < end; i++) {
        rowptr[i] = running;
        cursor[i] = running;
        running += deg[i];
    }
    if (t == 1023) rowptr[kN] = sm[1023];
}

__global__ __launch_bounds__(256) void scatter_kernel(
    const int* __restrict__ srcI, const int* __restrict__ dstI,
    int* __restrict__ cursor, int* __restrict__ esrc, int* __restrict__ eidx)
{
    const int e = blockIdx.x * 256 + threadIdx.x;
    if (e >= kE) return;
    const int d = dstI[e];
    const int pos = atomicAdd(&cursor[d], 1);
    esrc[pos] = srcI[e];
    eidx[pos] = e;
}

// ---------------- Fused per-node aggregation + epilogue ---------------------
// 1 wave = 1 dst node; lane handles channels (2*lane, 2*lane+1); 16-lane = head.
__global__ __launch_bounds__(256) void fused_kernel(
    const float* __restrict__ q, const float* __restrict__ kk,
    const float* __restrict__ vv, const float* __restrict__ ea,
    const float* __restrict__ We, const float* __restrict__ be,
    const int* __restrict__ rowptr, const int* __restrict__ esrc,
    const int* __restrict__ eidx,
    const float* __restrict__ xr, const float* __restrict__ Wb,
    const float* __restrict__ lnw, const float* __restrict__ lnb,
    float* __restrict__ hout)
{
    const int t = threadIdx.x;
    const int n = blockIdx.x * 4 + (t >> 6);
    if (n >= kN) return;
    const int lane = t & 63;
    const int c = lane << 1;

    // loop-invariant: We column slice, bias, own query
    float we0[kED], we1[kED];
#pragma unroll
    for (int j = 0; j < kED; j++) {
        const float2 w = *(const float2*)&We[j * kHC + c];
        we0[j] = w.x; we1[j] = w.y;
    }
    const float be0 = be[c], be1 = be[c + 1];
    const float2 qv = *(const float2*)&q[(size_t)n * kHC + c];

    float acc0 = 0.f, acc1 = 0.f, den = 0.f;
    const int beg = rowptr[n], endp = rowptr[n + 1];
    for (int jj = beg; jj < endp; jj++) {
        const int s   = esrc[jj];
        const int eid = eidx[jj];
        const float a = ea[(size_t)eid * kED + (lane & 31)];
        float e0 = be0, e1 = be1;
#pragma unroll
        for (int j = 0; j < kED; j++) {
            const float aj = __shfl(a, j, 32);
            e0 = fmaf(aj, we0[j], e0);
            e1 = fmaf(aj, we1[j], e1);
        }
        const float2 kv = *(const float2*)&kk[(size_t)s * kHC + c];
        const float2 vl = *(const float2*)&vv[(size_t)s * kHC + c];
        float p = qv.x * (kv.x + e0) + qv.y * (kv.y + e1);
        p += __shfl_xor(p, 1);
        p += __shfl_xor(p, 2);
        p += __shfl_xor(p, 4);
        p += __shfl_xor(p, 8);
        const float aex = __expf(p * RSQRT_C);
        den += aex;
        acc0 = fmaf(vl.x + e0, aex, acc0);
        acc1 = fmaf(vl.y + e1, aex, acc1);
    }
    const float invd = 1.f / (den + 1e-16f);
    const float o0 = acc0 * invd, o1 = acc1 * invd;

    const float2 r = *(const float2*)&xr[(size_t)n * kHC + c];
    float z = o0 * Wb[c] + o1 * Wb[c + 1]
            + r.x * Wb[kHC + c] + r.y * Wb[kHC + c + 1]
            + (o0 - r.x) * Wb[2 * kHC + c] + (o1 - r.y) * Wb[2 * kHC + c + 1];
#pragma unroll
    for (int m = 1; m < 64; m <<= 1) z += __shfl_xor(z, m);
    const float beta = 1.f / (1.f + __expf(-z));

    const float g0 = beta * r.x + (1.f - beta) * o0;
    const float g1 = beta * r.y + (1.f - beta) * o1;

    float sm = g0 + g1;
    float sq = g0 * g0 + g1 * g1;
#pragma unroll
    for (int m = 1; m < 64; m <<= 1) {
        sm += __shfl_xor(sm, m);
        sq += __shfl_xor(sq, m);
    }
    const float mu  = sm * (1.f / kHC);
    const float var = sq * (1.f / kHC) - mu * mu;
    const float inv = rsqrtf(var + EPS_LN);

    float y0 = (g0 - mu) * inv * lnw[c] + lnb[c];
    float y1 = (g1 - mu) * inv * lnw[c + 1] + lnb[c + 1];
    y0 = y0 > 0.f ? y0 : NEG_SLOPE * y0;
    y1 = y1 > 0.f ? y1 : NEG_SLOPE * y1;
    *(float2*)&hout[(size_t)n * kHC + c] = make_float2(y0, y1);
}

extern "C" void kernel_launch(void* const* d_in, const int* in_sizes, int n_in,
                              void* d_out, int out_size, void* d_ws, size_t ws_size,
                              hipStream_t stream)
{
    const float* x   = (const float*)d_in[0];
    const int*   ei  = (const int*)d_in[1];     // int64 in reference -> int32 here
    const float* ea  = (const float*)d_in[2];
    const float* Wq  = (const float*)d_in[3];
    const float* bq  = (const float*)d_in[4];
    const float* Wk  = (const float*)d_in[5];
    const float* bk  = (const float*)d_in[6];
    const float* Wv  = (const float*)d_in[7];
    const float* bv  = (const float*)d_in[8];
    const float* We  = (const float*)d_in[9];
    const float* be  = (const float*)d_in[10];
    const float* Wsk = (const float*)d_in[11];
    const float* bsk = (const float*)d_in[12];
    const float* Wb  = (const float*)d_in[13];
    const float* lnw = (const float*)d_in[14];
    const float* lnb = (const float*)d_in[15];
    float* out = (float*)d_out;

    float* ws = (float*)d_ws;
    float* q  = ws;
    float* k  = q  + (size_t)kN * kHC;
    float* v  = k  + (size_t)kN * kHC;
    float* xr = v  + (size_t)kN * kHC;
    int* deg    = (int*)(xr + (size_t)kN * kHC);
    int* rowptr = deg + kN;
    int* cursor = rowptr + kN + 1;
    int* esrc   = cursor + kN;
    int* eidx   = esrc + kE;

    const int* srcI = ei;
    const int* dstI = ei + kE;

    // ---- CSR build (edge_index constant across layers) ----
    hipMemsetAsync(deg, 0, (size_t)kN * sizeof(int), stream);
    hist_kernel<<<(kE + 255) / 256, 256, 0, stream>>>(dstI, deg);
    scan_kernel<<<1, 1024, 0, stream>>>(deg, rowptr, cursor);
    scatter_kernel<<<(kE + 255) / 256, 256, 0, stream>>>(srcI, dstI, cursor, esrc, eidx);

    const float* hin = x;
    for (int l = 0; l < kL; l++) {
        proj_kernel<<<kN / 16, 256, 0, stream>>>(
            hin,
            Wq + (size_t)l * kHC * kHC, bq + (size_t)l * kHC,
            Wk + (size_t)l * kHC * kHC, bk + (size_t)l * kHC,
            Wv + (size_t)l * kHC * kHC, bv + (size_t)l * kHC,
            Wsk + (size_t)l * kHC * kHC, bsk + (size_t)l * kHC,
            q, k, v, xr);
        fused_kernel<<<(kN + 3) / 4, 256, 0, stream>>>(
            q, k, v, ea,
            We + (size_t)l * kED * kHC, be + (size_t)l * kHC,
            rowptr, esrc, eidx,
            xr, Wb + (size_t)l * 3 * kHC,
            lnw + (size_t)l * kHC, lnb + (size_t)l * kHC,
            out);
        hin = out;
    }
}